// Round 9
// baseline (474.909 us; speedup 1.0000x reference)
//
#include <hip/hip_runtime.h>
#include <hip/hip_bf16.h>

typedef __hip_bfloat16 bf16;
typedef __attribute__((ext_vector_type(4))) float f32x4;
typedef __attribute__((ext_vector_type(8))) short s16x8;
typedef __attribute__((ext_vector_type(4))) unsigned short u16x4;

#define NB 64
#define NT 197
#define DIM 768
#define NH 12
#define HQKV 3072
#define DH 1536
#define DV 128
#define MREAL (NB*NT)      // 12608
#define MPAD 12800         // 100*128
#define KPAD 224           // padded key count
#define PSTR 232           // P-tile LDS row stride
#define CNT ((float)MREAL)

__device__ __forceinline__ float bf2f(bf16 v) { return __bfloat162float(v); }
__device__ __forceinline__ bf16  f2bf(float v){ return __float2bfloat16(v); }
__device__ __forceinline__ unsigned short f2bfu(float v){ return __builtin_bit_cast(unsigned short, __float2bfloat16(v)); }
__device__ __forceinline__ float u2f(unsigned short u){ return __builtin_bit_cast(float, (unsigned)u << 16); }

// async global->LDS, 16B per lane; LDS dest wave-uniform base (HW adds lane*16)
__device__ __forceinline__ void async16(const bf16* g, bf16* l) {
  __builtin_amdgcn_global_load_lds((const __attribute__((address_space(1))) void*)g,
                                   (__attribute__((address_space(3))) void*)l, 16, 0, 0);
}

// ---------------- prep: vectorized f32->bf16 converts, zero pads/stats/cls ----------------
__global__ void prep_kernel(const float* __restrict__ x, const float* __restrict__ qkv_w,
                            const float* __restrict__ proj_w,
                            bf16* __restrict__ xb, bf16* __restrict__ wqkvb,
                            bf16* __restrict__ wprojb, bf16* __restrict__ act,
                            bf16* __restrict__ vT,
                            float* __restrict__ statq, float* __restrict__ statp,
                            float* __restrict__ cls)
{
  const int stride = gridDim.x * blockDim.x;
  const int tid = blockIdx.x * blockDim.x + threadIdx.x;
  const u16x4 z4 = {0,0,0,0};
  for (int i = tid; i < MREAL*DIM/4; i += stride) {
    float4 v = ((const float4*)x)[i];
    u16x4 o = {f2bfu(v.x), f2bfu(v.y), f2bfu(v.z), f2bfu(v.w)};
    ((u16x4*)xb)[i] = o;
  }
  for (int i = tid; i < (MPAD-MREAL)*DIM/4; i += stride)
    ((u16x4*)(xb + (size_t)MREAL*DIM))[i] = z4;
  for (int i = tid; i < HQKV*DIM/4; i += stride) {
    float4 v = ((const float4*)qkv_w)[i];
    u16x4 o = {f2bfu(v.x), f2bfu(v.y), f2bfu(v.z), f2bfu(v.w)};
    ((u16x4*)wqkvb)[i] = o;
  }
  for (int i = tid; i < DIM*DH/4; i += stride) {
    float4 v = ((const float4*)proj_w)[i];
    u16x4 o = {f2bfu(v.x), f2bfu(v.y), f2bfu(v.z), f2bfu(v.w)};
    ((u16x4*)wprojb)[i] = o;
  }
  for (int i = tid; i < (MPAD-MREAL)*DH/4; i += stride)
    ((u16x4*)(act + (size_t)MREAL*DH))[i] = z4;
  // zero V^T pad columns (keys 197..223)
  for (int i = tid; i < NB*NH*DV*(KPAD-NT); i += stride) {
    int r = i / (KPAD-NT), c = NT + (i - r*(KPAD-NT));
    vT[(size_t)r*KPAD + c] = f2bf(0.f);
  }
  for (int i = tid; i < 2*HQKV; i += stride) statq[i] = 0.f;
  for (int i = tid; i < 2*DIM;  i += stride) statp[i] = 0.f;
  for (int i = tid; i < NB*(NT-1); i += stride) cls[i] = 0.f;
}

// ---------------- GEMM: m97 structure, 4 blocks/CU ----------------
// 128x128 tile, BK=32, 4 waves (2Mx2N), 2-slot LDS dbuf (32 KB), stage-next-then-compute,
// plain __syncthreads drain. 4 blocks/CU -> cross-block overlap hides the drain (m114).
// VT mode: odd col-tiles (v-half of head) write transposed V^T[b,h][d][tok] instead of C.
template<int K, int NT_TILES, bool VT, bool SWZ>
__global__ __launch_bounds__(256, 4)
void gemm_m97(const bf16* __restrict__ A, const bf16* __restrict__ Bw,
              bf16* __restrict__ C, bf16* __restrict__ vT,
              float* __restrict__ stats, int Ncols, int nblk)
{
  constexpr int NKT = K/32;
  __shared__ bf16 As[2][128*32];   // 16 KB
  __shared__ bf16 Bs[2][128*32];   // 16 KB
  int bid = blockIdx.x;
  if (SWZ) bid = (bid & 7) * (nblk >> 3) + (bid >> 3);   // nblk % 8 == 0
  const int bn = bid % NT_TILES;
  const int bm = bid / NT_TILES;
  const int t = threadIdx.x;
  const int wave = t >> 6, lane = t & 63;
  const int wm = wave >> 1, wn = wave & 1;
  const int l15 = lane & 15, l4 = lane >> 4;

  const int sr = t >> 2;
  const bf16* aG = A  + (size_t)(bm*128 + sr)*K + (t&3)*8;
  const bf16* bG = Bw + (size_t)(bn*128 + sr)*K + (t&3)*8;
  const int ldsOff = wave * 512;   // elems; HW adds lane*16B

  auto stage = [&](int slot, int kt) {
    async16(aG + kt*32,                &As[slot][ldsOff]);
    async16(aG + kt*32 + (size_t)64*K, &As[slot][ldsOff + 2048]);
    async16(bG + kt*32,                &Bs[slot][ldsOff]);
    async16(bG + kt*32 + (size_t)64*K, &Bs[slot][ldsOff + 2048]);
  };

  f32x4 acc[4][4] = {};
  stage(0, 0);
  __syncthreads();
  for (int kt = 0; kt < NKT; ++kt) {
    if (kt + 1 < NKT) stage((kt + 1) & 1, kt + 1);
    const bf16* as = As[kt & 1];
    const bf16* bs = Bs[kt & 1];
    s16x8 af[4], bfr[4];
#pragma unroll
    for (int i = 0; i < 4; ++i) af[i]  = *(const s16x8*)&as[(wm*64 + i*16 + l15)*32 + l4*8];
#pragma unroll
    for (int i = 0; i < 4; ++i) bfr[i] = *(const s16x8*)&bs[(wn*64 + i*16 + l15)*32 + l4*8];
#pragma unroll
    for (int im = 0; im < 4; ++im)
#pragma unroll
      for (int in = 0; in < 4; ++in)
        acc[im][in] = __builtin_amdgcn_mfma_f32_16x16x32_bf16(af[im], bfr[in], acc[im][in], 0, 0, 0);
    __syncthreads();   // drains stage(kt+1) + publishes buffer to all waves
  }

  // ---------------- epilogue: C write (+stats) or V^T transpose (+stats) ----------------
  const int gRow0 = bm*128 + wm*64;
  const int colBase = bn*128 + wn*64;
  if (!VT || (bn & 1) == 0) {
#pragma unroll
    for (int n = 0; n < 4; ++n) {
      const int col = colBase + n*16 + l15;
      float s = 0.f, sq = 0.f;
#pragma unroll
      for (int m = 0; m < 4; ++m) {
        const int r0 = gRow0 + m*16 + l4*4;
        const bool wr = r0 < MREAL;   // r0%4==0, MREAL%4==0 -> whole group real
#pragma unroll
        for (int j = 0; j < 4; ++j) {
          float v = acc[m][n][j];
          s += v; sq += v*v;
          if (wr) C[(size_t)(r0 + j)*Ncols + col] = f2bf(v);
        }
      }
      s  += __shfl_xor(s, 16);  s  += __shfl_xor(s, 32);
      sq += __shfl_xor(sq, 16); sq += __shfl_xor(sq, 32);
      if (l4 == 0) { atomicAdd(&stats[col], s); atomicAdd(&stats[Ncols + col], sq); }
    }
  } else {
    const int hh = bn >> 1;   // head index (v half-tile)
#pragma unroll
    for (int n = 0; n < 4; ++n) {
      const int col = colBase + n*16 + l15;
      const int d = col & 127;
      float s = 0.f, sq = 0.f;
#pragma unroll
      for (int m = 0; m < 4; ++m) {
        const int r0 = gRow0 + m*16 + l4*4;
#pragma unroll
        for (int j = 0; j < 4; ++j) { float v = acc[m][n][j]; s += v; sq += v*v; }
        if (r0 < MREAL) {
          int b2 = r0 / 197;
          int n0 = r0 - b2*197;
          if (n0 <= NT-4) {
            bf16* dst = vT + ((size_t)((b2*NH + hh)*DV + d))*KPAD + n0;
#pragma unroll
            for (int j = 0; j < 4; ++j) dst[j] = f2bf(acc[m][n][j]);
          } else {
#pragma unroll
            for (int j = 0; j < 4; ++j) {
              int r = r0 + j; int b3 = r / 197; int nn = r - b3*197;
              vT[((size_t)((b3*NH + hh)*DV + d))*KPAD + nn] = f2bf(acc[m][n][j]);
            }
          }
        }
      }
      s  += __shfl_xor(s, 16);  s  += __shfl_xor(s, 32);
      sq += __shfl_xor(sq, 16); sq += __shfl_xor(sq, 32);
      if (l4 == 0) { atomicAdd(&stats[col], s); atomicAdd(&stats[Ncols + col], sq); }
    }
  }
}

// ---------------- BN stats -> scale/bias; for qkv also emit per-head (c,w) fold vectors ----
// softmax invariance: softmax((aq*q+bq).(ak*k+bk)) == softmax((c*q+w).k_raw) with
// c_d = SCALE*aq_d*ak_d, w_d = SCALE*bq_d*ak_d  (q-row-constant terms cancel).
__global__ void finalize_stats(const float* __restrict__ stats, const float* __restrict__ g,
                               const float* __restrict__ bb, float* __restrict__ sb, int F,
                               float* __restrict__ qcw)
{
  int f = blockIdx.x * blockDim.x + threadIdx.x;
  if (f >= F) return;
  float m   = stats[f] / CNT;
  float var = stats[F + f] / CNT - m*m;
  float scl = g[f] / sqrtf(var + 1e-5f);
  float bia = bb[f] - m*scl;
  sb[f] = scl;
  sb[F + f] = bia;
  if (qcw && (f & 255) < 64) {          // q-feature: pair with k-feature f+64
    float mk   = stats[f + 64] / CNT;
    float vark = stats[F + f + 64] / CNT - mk*mk;
    float sclk = g[f + 64] / sqrtf(vark + 1e-5f);
    int h = f >> 8, d = f & 63;
    qcw[h*128 + d]      = 0.125f * scl * sclk;   // c_d
    qcw[h*128 + 64 + d] = 0.125f * bia * sclk;   // w_d
  }
}

// ---------------- attention v9: ONE block per (b,h); 4 waves loop over 13 q-tiles --------
// K/V panels fetched once per (b,h) (no cross-block redundancy); 4 waves share panels
// through L1/L2. Raw q/k/v consumed directly: q~ = c*q_raw + w in-register; V raw with
// out = av*(P.Vraw) + bv in epilogue (sum_k P = 1). No barriers (per-wave P region).
__global__ __launch_bounds__(256, 4)
void attn_kernel(const bf16* __restrict__ qkv, const bf16* __restrict__ vT,
                 const float* __restrict__ sb, const float* __restrict__ qcw,
                 bf16* __restrict__ act, float* __restrict__ cls)
{
  __shared__ bf16 p_all[4*16*PSTR];   // 29.7 KB
  const int t = threadIdx.x;
  const int wave = t >> 6, lane = t & 63;
  const int l15 = lane & 15, l4 = lane >> 4;
  const int bh = blockIdx.x;
  const int b = bh / NH, h = bh - b*NH;
  const size_t rowBase = (size_t)b * NT;
  bf16* p_lds = &p_all[wave * (16*PSTR)];
  const bf16* Qp = qkv + rowBase*HQKV + h*256;
  const bf16* Kp = Qp + 64;
  const bf16* Vp = vT + (size_t)bh*DV*KPAD;
  const int fv = h*256 + 128;

  // per-lane BN fold vectors (8 q-dims per fragment half), hoisted out of the tile loop
  f32x4 c0a = *(const f32x4*)&qcw[h*128 + l4*8],      c0b = *(const f32x4*)&qcw[h*128 + l4*8 + 4];
  f32x4 w0a = *(const f32x4*)&qcw[h*128 + 64 + l4*8], w0b = *(const f32x4*)&qcw[h*128 + 64 + l4*8 + 4];
  f32x4 c1a = *(const f32x4*)&qcw[h*128 + 32 + l4*8], c1b = *(const f32x4*)&qcw[h*128 + 32 + l4*8 + 4];
  f32x4 w1a = *(const f32x4*)&qcw[h*128 + 96 + l4*8], w1b = *(const f32x4*)&qcw[h*128 + 96 + l4*8 + 4];

  for (int ti = wave; ti < 13; ti += 4) {
    const int q0 = ti * 16;

    // raw q frags + in-register BN fold
    s16x8 aq0 = *(const s16x8*)&Qp[(size_t)(q0 + l15)*HQKV + l4*8];
    s16x8 aq1 = *(const s16x8*)&Qp[(size_t)(q0 + l15)*HQKV + 32 + l4*8];
    {
      s16x8 r0, r1;
#pragma unroll
      for (int j = 0; j < 4; ++j) {
        r0[j]   = (short)f2bfu(u2f((unsigned short)aq0[j])   * c0a[j] + w0a[j]);
        r0[j+4] = (short)f2bfu(u2f((unsigned short)aq0[j+4]) * c0b[j] + w0b[j]);
        r1[j]   = (short)f2bfu(u2f((unsigned short)aq1[j])   * c1a[j] + w1a[j]);
        r1[j+4] = (short)f2bfu(u2f((unsigned short)aq1[j+4]) * c1b[j] + w1b[j]);
      }
      aq0 = r0; aq1 = r1;
    }

    f32x4 scr[14];
#pragma unroll
    for (int kt = 0; kt < 14; ++kt) {
      s16x8 bk0 = *(const s16x8*)&Kp[(size_t)(kt*16 + l15)*HQKV + l4*8];
      s16x8 bk1 = *(const s16x8*)&Kp[(size_t)(kt*16 + l15)*HQKV + 32 + l4*8];
      f32x4 z = {};
      z = __builtin_amdgcn_mfma_f32_16x16x32_bf16(aq0, bk0, z, 0, 0, 0);
      scr[kt] = __builtin_amdgcn_mfma_f32_16x16x32_bf16(aq1, bk1, z, 0, 0, 0);
    }

    float mx[4] = {-1e30f, -1e30f, -1e30f, -1e30f}, sm[4];
#pragma unroll
    for (int kt = 0; kt < 14; ++kt) {
      int colv = kt*16 + l15;
#pragma unroll
      for (int j = 0; j < 4; ++j) {
        if (colv >= NT) scr[kt][j] = -1e30f;
        mx[j] = fmaxf(mx[j], scr[kt][j]);
      }
    }
#pragma unroll
    for (int j = 0; j < 4; ++j) {
      mx[j] = fmaxf(mx[j], __shfl_xor(mx[j], 1));
      mx[j] = fmaxf(mx[j], __shfl_xor(mx[j], 2));
      mx[j] = fmaxf(mx[j], __shfl_xor(mx[j], 4));
      mx[j] = fmaxf(mx[j], __shfl_xor(mx[j], 8));
      sm[j] = 0.f;
    }
#pragma unroll
    for (int kt = 0; kt < 14; ++kt)
#pragma unroll
      for (int j = 0; j < 4; ++j) { float e = __expf(scr[kt][j] - mx[j]); scr[kt][j] = e; sm[j] += e; }
#pragma unroll
    for (int j = 0; j < 4; ++j) {
      sm[j] += __shfl_xor(sm[j], 1);
      sm[j] += __shfl_xor(sm[j], 2);
      sm[j] += __shfl_xor(sm[j], 4);
      sm[j] += __shfl_xor(sm[j], 8);
      sm[j] = 1.f / sm[j];
    }
    if (ti == 0 && l4 == 0) {   // query 0 lives in tile 0 (wave 0)
#pragma unroll
      for (int kt = 0; kt < 14; ++kt) {
        int colv = kt*16 + l15;
        if (colv >= 1 && colv < NT)
          atomicAdd(&cls[b*(NT-1) + colv - 1], scr[kt][0] * sm[0] * (1.f/NH));
      }
    }
#pragma unroll
    for (int kt = 0; kt < 14; ++kt) {
      int colv = kt*16 + l15;
#pragma unroll
      for (int j = 0; j < 4; ++j)
        p_lds[(l4*4 + j)*PSTR + colv] = f2bf(scr[kt][j] * sm[j]);
    }

    f32x4 ao[8] = {};
#pragma unroll
    for (int ks = 0; ks < 7; ++ks) {
      s16x8 ap = *(const s16x8*)&p_lds[l15*PSTR + ks*32 + l4*8];
#pragma unroll
      for (int dt = 0; dt < 8; ++dt) {
        s16x8 bv = *(const s16x8*)&Vp[(size_t)(dt*16 + l15)*KPAD + ks*32 + l4*8];
        ao[dt] = __builtin_amdgcn_mfma_f32_16x16x32_bf16(ap, bv, ao[dt], 0, 0, 0);
      }
    }
#pragma unroll
    for (int dt = 0; dt < 8; ++dt) {
      const int d = dt*16 + l15;
      const float av = sb[fv + d];
      const float bv = sb[HQKV + fv + d];
#pragma unroll
      for (int j = 0; j < 4; ++j) {
        int q = q0 + l4*4 + j;
        if (q < NT) {
          float v = ao[dt][j] * av + bv;
          float hs = v * fminf(fmaxf(v + 3.f, 0.f), 6.f) * (1.f/6.f);
          act[(rowBase + q)*DH + h*DV + d] = f2bf(hs);
        }
      }
    }
  }
}

// ---------------- final BN apply -> f32 out ----------------
__global__ void apply_bn(const bf16* __restrict__ y, const float* __restrict__ sb,
                         float* __restrict__ out)
{
  const int stride = gridDim.x * blockDim.x;
  for (int i = blockIdx.x * blockDim.x + threadIdx.x; i < MREAL*DIM/4; i += stride) {
    int c = (i*4) % DIM;
    u16x4 yv = *(const u16x4*)&y[(size_t)i*4];
    float4 o;
    o.x = u2f(yv.x) * sb[c]     + sb[DIM + c];
    o.y = u2f(yv.y) * sb[c + 1] + sb[DIM + c + 1];
    o.z = u2f(yv.z) * sb[c + 2] + sb[DIM + c + 2];
    o.w = u2f(yv.w) * sb[c + 3] + sb[DIM + c + 3];
    *(float4*)&out[(size_t)i*4] = o;
  }
}

extern "C" void kernel_launch(void* const* d_in, const int* in_sizes, int n_in,
                              void* d_out, int out_size, void* d_ws, size_t ws_size,
                              hipStream_t stream)
{
  const float* x      = (const float*)d_in[0];
  const float* qkv_w  = (const float*)d_in[1];
  const float* qkv_g  = (const float*)d_in[2];
  const float* qkv_b  = (const float*)d_in[3];
  const float* proj_w = (const float*)d_in[4];
  const float* proj_g = (const float*)d_in[5];
  const float* proj_b = (const float*)d_in[6];
  float* y_out   = (float*)d_out;
  float* cls_out = y_out + (size_t)MREAL * DIM;

  char* ws = (char*)d_ws;
  size_t off = 0;
  auto alloc = [&](size_t bytes) { void* p = ws + off; off += (bytes + 255) & ~(size_t)255; return p; };
  bf16* xb      = (bf16*)alloc((size_t)MPAD * DIM * 2);
  bf16* wqkvb   = (bf16*)alloc((size_t)HQKV * DIM * 2);
  bf16* wprojb  = (bf16*)alloc((size_t)DIM * DH * 2);
  bf16* qkv_raw = (bf16*)alloc((size_t)MPAD * HQKV * 2);
  bf16* act     = (bf16*)alloc((size_t)MPAD * DH * 2);
  bf16* y_raw   = (bf16*)alloc((size_t)MPAD * DIM * 2);
  bf16* vT      = (bf16*)alloc((size_t)NB * NH * DV * KPAD * 2);
  float* statq  = (float*)alloc((size_t)2 * HQKV * 4);
  float* sbq    = (float*)alloc((size_t)2 * HQKV * 4);
  float* statp  = (float*)alloc((size_t)2 * DIM * 4);
  float* sbp    = (float*)alloc((size_t)2 * DIM * 4);
  float* qcw    = (float*)alloc((size_t)NH * 128 * 4);

  prep_kernel<<<2048, 256, 0, stream>>>(x, qkv_w, proj_w, xb, wqkvb, wprojb, act, vT,
                                        statq, statp, cls_out);
  // qkv GEMM: 100 x 24 = 2400 blocks (2400 % 8 == 0 -> XCD swizzle on)
  gemm_m97<DIM, HQKV/128, true, true><<<(MPAD/128)*(HQKV/128), 256, 0, stream>>>(
      xb, wqkvb, qkv_raw, vT, statq, HQKV, (MPAD/128)*(HQKV/128));
  finalize_stats<<<HQKV/256, 256, 0, stream>>>(statq, qkv_g, qkv_b, sbq, HQKV, qcw);
  // attention: one block per (b,h) = 768 blocks, 3/CU fully resident
  attn_kernel<<<NB*NH, 256, 0, stream>>>(qkv_raw, vT, sbq, qcw, act, cls_out);
  // proj GEMM: 100 x 6 = 600 blocks (swizzle on)
  gemm_m97<DH, DIM/128, false, true><<<(MPAD/128)*(DIM/128), 256, 0, stream>>>(
      act, wprojb, y_raw, nullptr, statp, DIM, (MPAD/128)*(DIM/128));
  finalize_stats<<<DIM/256, 256, 0, stream>>>(statp, proj_g, proj_b, sbp, DIM, nullptr);
  apply_bn<<<2048, 256, 0, stream>>>(y_raw, sbp, y_out);
}

// Round 10
// 225.093 us; speedup vs baseline: 2.1098x; 2.1098x over previous
//
#include <hip/hip_runtime.h>
#include <hip/hip_bf16.h>

typedef __hip_bfloat16 bf16;
typedef __attribute__((ext_vector_type(4))) float f32x4;
typedef __attribute__((ext_vector_type(8))) short s16x8;
typedef __attribute__((ext_vector_type(4))) unsigned short u16x4;

#define NB 64
#define NT 197
#define DIM 768
#define NH 12
#define HQKV 3072
#define DH 1536
#define DV 128
#define MREAL (NB*NT)      // 12608
#define MPAD 12800         // 100*128
#define KPAD 224           // padded key count
#define PSTR 232           // P-tile LDS row stride
#define CNT ((float)MREAL)

__device__ __forceinline__ float bf2f(bf16 v) { return __bfloat162float(v); }
__device__ __forceinline__ bf16  f2bf(float v){ return __float2bfloat16(v); }
__device__ __forceinline__ unsigned short f2bfu(float v){ return __builtin_bit_cast(unsigned short, __float2bfloat16(v)); }
__device__ __forceinline__ float u2f(unsigned short u){ return __builtin_bit_cast(float, (unsigned)u << 16); }

// async global->LDS, 16B per lane; LDS dest wave-uniform base (HW adds lane*16)
__device__ __forceinline__ void async16(const bf16* g, bf16* l) {
  __builtin_amdgcn_global_load_lds((const __attribute__((address_space(1))) void*)g,
                                   (__attribute__((address_space(3))) void*)l, 16, 0, 0);
}

// ---------------- prep: vectorized f32->bf16 converts, zero pads/stats/cls ----------------
__global__ void prep_kernel(const float* __restrict__ x, const float* __restrict__ qkv_w,
                            const float* __restrict__ proj_w,
                            bf16* __restrict__ xb, bf16* __restrict__ wqkvb,
                            bf16* __restrict__ wprojb, bf16* __restrict__ act,
                            bf16* __restrict__ vT,
                            float* __restrict__ statq, float* __restrict__ statp,
                            float* __restrict__ cls)
{
  const int stride = gridDim.x * blockDim.x;
  const int tid = blockIdx.x * blockDim.x + threadIdx.x;
  const u16x4 z4 = {0,0,0,0};
  for (int i = tid; i < MREAL*DIM/4; i += stride) {
    float4 v = ((const float4*)x)[i];
    u16x4 o = {f2bfu(v.x), f2bfu(v.y), f2bfu(v.z), f2bfu(v.w)};
    ((u16x4*)xb)[i] = o;
  }
  for (int i = tid; i < (MPAD-MREAL)*DIM/4; i += stride)
    ((u16x4*)(xb + (size_t)MREAL*DIM))[i] = z4;
  for (int i = tid; i < HQKV*DIM/4; i += stride) {
    float4 v = ((const float4*)qkv_w)[i];
    u16x4 o = {f2bfu(v.x), f2bfu(v.y), f2bfu(v.z), f2bfu(v.w)};
    ((u16x4*)wqkvb)[i] = o;
  }
  for (int i = tid; i < DIM*DH/4; i += stride) {
    float4 v = ((const float4*)proj_w)[i];
    u16x4 o = {f2bfu(v.x), f2bfu(v.y), f2bfu(v.z), f2bfu(v.w)};
    ((u16x4*)wprojb)[i] = o;
  }
  for (int i = tid; i < (MPAD-MREAL)*DH/4; i += stride)
    ((u16x4*)(act + (size_t)MREAL*DH))[i] = z4;
  // zero V^T pad columns (keys 197..223)
  for (int i = tid; i < NB*NH*DV*(KPAD-NT); i += stride) {
    int r = i / (KPAD-NT), c = NT + (i - r*(KPAD-NT));
    vT[(size_t)r*KPAD + c] = f2bf(0.f);
  }
  for (int i = tid; i < 2*HQKV; i += stride) statq[i] = 0.f;
  for (int i = tid; i < 2*DIM;  i += stride) statp[i] = 0.f;
  for (int i = tid; i < NB*(NT-1); i += stride) cls[i] = 0.f;
}

// ---------------- GEMM: m97 structure, 4 blocks/CU ----------------
// 128x128 tile, BK=32, 4 waves (2Mx2N), 2-slot LDS dbuf (32 KB), stage-next-then-compute,
// plain __syncthreads drain. 4 blocks/CU -> cross-block overlap hides the drain (m114).
// VT mode: odd col-tiles (v-half of head) write transposed V^T[b,h][d][tok] instead of C.
template<int K, int NT_TILES, bool VT, bool SWZ>
__global__ __launch_bounds__(256, 4)
void gemm_m97(const bf16* __restrict__ A, const bf16* __restrict__ Bw,
              bf16* __restrict__ C, bf16* __restrict__ vT,
              float* __restrict__ stats, int Ncols, int nblk)
{
  constexpr int NKT = K/32;
  __shared__ bf16 As[2][128*32];   // 16 KB
  __shared__ bf16 Bs[2][128*32];   // 16 KB
  int bid = blockIdx.x;
  if (SWZ) bid = (bid & 7) * (nblk >> 3) + (bid >> 3);   // nblk % 8 == 0
  const int bn = bid % NT_TILES;
  const int bm = bid / NT_TILES;
  const int t = threadIdx.x;
  const int wave = t >> 6, lane = t & 63;
  const int wm = wave >> 1, wn = wave & 1;
  const int l15 = lane & 15, l4 = lane >> 4;

  const int sr = t >> 2;
  const bf16* aG = A  + (size_t)(bm*128 + sr)*K + (t&3)*8;
  const bf16* bG = Bw + (size_t)(bn*128 + sr)*K + (t&3)*8;
  const int ldsOff = wave * 512;   // elems; HW adds lane*16B

  auto stage = [&](int slot, int kt) {
    async16(aG + kt*32,                &As[slot][ldsOff]);
    async16(aG + kt*32 + (size_t)64*K, &As[slot][ldsOff + 2048]);
    async16(bG + kt*32,                &Bs[slot][ldsOff]);
    async16(bG + kt*32 + (size_t)64*K, &Bs[slot][ldsOff + 2048]);
  };

  f32x4 acc[4][4] = {};
  stage(0, 0);
  __syncthreads();
  for (int kt = 0; kt < NKT; ++kt) {
    if (kt + 1 < NKT) stage((kt + 1) & 1, kt + 1);
    const bf16* as = As[kt & 1];
    const bf16* bs = Bs[kt & 1];
    s16x8 af[4], bfr[4];
#pragma unroll
    for (int i = 0; i < 4; ++i) af[i]  = *(const s16x8*)&as[(wm*64 + i*16 + l15)*32 + l4*8];
#pragma unroll
    for (int i = 0; i < 4; ++i) bfr[i] = *(const s16x8*)&bs[(wn*64 + i*16 + l15)*32 + l4*8];
#pragma unroll
    for (int im = 0; im < 4; ++im)
#pragma unroll
      for (int in = 0; in < 4; ++in)
        acc[im][in] = __builtin_amdgcn_mfma_f32_16x16x32_bf16(af[im], bfr[in], acc[im][in], 0, 0, 0);
    __syncthreads();   // drains stage(kt+1) + publishes buffer to all waves
  }

  // ---------------- epilogue: C write (+stats) or V^T transpose (+stats) ----------------
  const int gRow0 = bm*128 + wm*64;
  const int colBase = bn*128 + wn*64;
  if (!VT || (bn & 1) == 0) {
#pragma unroll
    for (int n = 0; n < 4; ++n) {
      const int col = colBase + n*16 + l15;
      float s = 0.f, sq = 0.f;
#pragma unroll
      for (int m = 0; m < 4; ++m) {
        const int r0 = gRow0 + m*16 + l4*4;
        const bool wr = r0 < MREAL;   // r0%4==0, MREAL%4==0 -> whole group real
#pragma unroll
        for (int j = 0; j < 4; ++j) {
          float v = acc[m][n][j];
          s += v; sq += v*v;
          if (wr) C[(size_t)(r0 + j)*Ncols + col] = f2bf(v);
        }
      }
      s  += __shfl_xor(s, 16);  s  += __shfl_xor(s, 32);
      sq += __shfl_xor(sq, 16); sq += __shfl_xor(sq, 32);
      if (l4 == 0) { atomicAdd(&stats[col], s); atomicAdd(&stats[Ncols + col], sq); }
    }
  } else {
    const int hh = bn >> 1;   // head index (v half-tile)
#pragma unroll
    for (int n = 0; n < 4; ++n) {
      const int col = colBase + n*16 + l15;
      const int d = col & 127;
      float s = 0.f, sq = 0.f;
#pragma unroll
      for (int m = 0; m < 4; ++m) {
        const int r0 = gRow0 + m*16 + l4*4;
#pragma unroll
        for (int j = 0; j < 4; ++j) { float v = acc[m][n][j]; s += v; sq += v*v; }
        if (r0 < MREAL) {
          int b2 = r0 / 197;
          int n0 = r0 - b2*197;
          if (n0 <= NT-4) {
            bf16* dst = vT + ((size_t)((b2*NH + hh)*DV + d))*KPAD + n0;
#pragma unroll
            for (int j = 0; j < 4; ++j) dst[j] = f2bf(acc[m][n][j]);
          } else {
#pragma unroll
            for (int j = 0; j < 4; ++j) {
              int r = r0 + j; int b3 = r / 197; int nn = r - b3*197;
              vT[((size_t)((b3*NH + hh)*DV + d))*KPAD + nn] = f2bf(acc[m][n][j]);
            }
          }
        }
      }
      s  += __shfl_xor(s, 16);  s  += __shfl_xor(s, 32);
      sq += __shfl_xor(sq, 16); sq += __shfl_xor(sq, 32);
      if (l4 == 0) { atomicAdd(&stats[col], s); atomicAdd(&stats[Ncols + col], sq); }
    }
  }
}

// ---------------- BN stats -> scale/bias; for qkv also emit per-head (c,w) fold vectors ----
// softmax invariance: softmax((aq*q+bq).(ak*k+bk)) == softmax((c*q+w).k_raw) with
// c_d = SCALE*aq_d*ak_d, w_d = SCALE*bq_d*ak_d  (q-row-constant terms cancel).
__global__ void finalize_stats(const float* __restrict__ stats, const float* __restrict__ g,
                               const float* __restrict__ bb, float* __restrict__ sb, int F,
                               float* __restrict__ qcw)
{
  int f = blockIdx.x * blockDim.x + threadIdx.x;
  if (f >= F) return;
  float m   = stats[f] / CNT;
  float var = stats[F + f] / CNT - m*m;
  float scl = g[f] / sqrtf(var + 1e-5f);
  float bia = bb[f] - m*scl;
  sb[f] = scl;
  sb[F + f] = bia;
  if (qcw && (f & 255) < 64) {          // q-feature: pair with k-feature f+64
    float mk   = stats[f + 64] / CNT;
    float vark = stats[F + f + 64] / CNT - mk*mk;
    float sclk = g[f + 64] / sqrtf(vark + 1e-5f);
    int h = f >> 8, d = f & 63;
    qcw[h*128 + d]      = 0.125f * scl * sclk;   // c_d
    qcw[h*128 + 64 + d] = 0.125f * bia * sclk;   // w_d
  }
}

// ---------------- attention v10: K,V^T staged in LDS once per (b,h); 8 waves ----------------
// K_lds [224][64] XOR-swizzled (granule ^= row&7), staged via global_load_lds with
// pre-swizzled SOURCE (linear dest -- rule: same involution on write-source and read).
// V_lds [128][256] (row-padded so the 3-bit XOR stays within the row; slots that the XOR
// maps out of [0,28) are written-with-garbage AND never read -- consistent by involution).
// Each wave independently processes q-tiles ti = wave, wave+8 (13 tiles of 16 queries).
// Raw q: q~ = c*q+w in-register; V raw with out = av*(P.Vraw)+bv (sum_k P = 1).
__global__ __launch_bounds__(512, 1)
void attn_kernel(const bf16* __restrict__ qkv, const bf16* __restrict__ vT,
                 const float* __restrict__ sb, const float* __restrict__ qcw,
                 bf16* __restrict__ act, float* __restrict__ cls)
{
  __shared__ bf16 k_lds[KPAD*64];     // 28 KB
  __shared__ bf16 v_lds[DV*256];      // 64 KB
  __shared__ bf16 p_all[8*16*PSTR];   // 59.4 KB
  const int t = threadIdx.x;
  const int wave = t >> 6, lane = t & 63;
  const int l15 = lane & 15, l4 = lane >> 4;
  const int bh = blockIdx.x;
  const int b = bh / NH, h = bh - b*NH;
  const size_t rowBase = (size_t)b * NT;
  bf16* p_lds = &p_all[wave * (16*PSTR)];
  const bf16* Qp = qkv + rowBase*HQKV + h*256;
  const bf16* Kp = Qp + 64;
  const bf16* Vp = vT + (size_t)bh*DV*KPAD;
  const int fv = h*256 + 128;

  // ---- stage K: 224 rows x 8 granules(16B); lambda = p*512 + t; src granule = g^(row&7)
  {
    const int ldsW = wave * 512;   // elems per wave chunk (64 lanes x 16B / 2B)
#pragma unroll
    for (int p = 0; p < 4; ++p) {
      int lam = p*512 + t;
      if (lam < KPAD*8) {
        int row = lam >> 3, g = lam & 7;
        async16(Kp + (size_t)row*HQKV + ((g ^ (row & 7))*8), &k_lds[p*4096 + ldsW]);
      }
    }
    // ---- stage V^T: 128 rows x 32 slots; src granule = slot^(row&7) (may read row tail
    //      overlap -- lands only in never-read slots; 62B OOB of vT for last bh lands in ws)
#pragma unroll
    for (int p = 0; p < 8; ++p) {
      int lam = p*512 + t;
      int r = lam >> 5, sl = lam & 31;
      async16(Vp + (size_t)r*KPAD + ((sl ^ (r & 7))*8), &v_lds[p*4096 + ldsW]);
    }
  }
  __syncthreads();   // drains vmcnt + publishes LDS

  // per-lane BN fold vectors for q
  f32x4 c0a = *(const f32x4*)&qcw[h*128 + l4*8],      c0b = *(const f32x4*)&qcw[h*128 + l4*8 + 4];
  f32x4 w0a = *(const f32x4*)&qcw[h*128 + 64 + l4*8], w0b = *(const f32x4*)&qcw[h*128 + 64 + l4*8 + 4];
  f32x4 c1a = *(const f32x4*)&qcw[h*128 + 32 + l4*8], c1b = *(const f32x4*)&qcw[h*128 + 32 + l4*8 + 4];
  f32x4 w1a = *(const f32x4*)&qcw[h*128 + 96 + l4*8], w1b = *(const f32x4*)&qcw[h*128 + 96 + l4*8 + 4];

  const int kswz = l15 & 7;   // row&7 for rows kt*16+l15 / dt*16+l15

  for (int ti = wave; ti < 13; ti += 8) {
    const int q0 = ti * 16;

    s16x8 aq0 = *(const s16x8*)&Qp[(size_t)(q0 + l15)*HQKV + l4*8];
    s16x8 aq1 = *(const s16x8*)&Qp[(size_t)(q0 + l15)*HQKV + 32 + l4*8];
    {
      s16x8 r0, r1;
#pragma unroll
      for (int j = 0; j < 4; ++j) {
        r0[j]   = (short)f2bfu(u2f((unsigned short)aq0[j])   * c0a[j] + w0a[j]);
        r0[j+4] = (short)f2bfu(u2f((unsigned short)aq0[j+4]) * c0b[j] + w0b[j]);
        r1[j]   = (short)f2bfu(u2f((unsigned short)aq1[j])   * c1a[j] + w1a[j]);
        r1[j+4] = (short)f2bfu(u2f((unsigned short)aq1[j+4]) * c1b[j] + w1b[j]);
      }
      aq0 = r0; aq1 = r1;
    }

    f32x4 scr[14];
#pragma unroll
    for (int kt = 0; kt < 14; ++kt) {
      const int krow = (kt*16 + l15)*64;
      s16x8 bk0 = *(const s16x8*)&k_lds[krow + ((l4 ^ kswz)*8)];
      s16x8 bk1 = *(const s16x8*)&k_lds[krow + (((4 + l4) ^ kswz)*8)];
      f32x4 z = {};
      z = __builtin_amdgcn_mfma_f32_16x16x32_bf16(aq0, bk0, z, 0, 0, 0);
      scr[kt] = __builtin_amdgcn_mfma_f32_16x16x32_bf16(aq1, bk1, z, 0, 0, 0);
    }

    float mx[4] = {-1e30f, -1e30f, -1e30f, -1e30f}, sm[4];
#pragma unroll
    for (int kt = 0; kt < 14; ++kt) {
      int colv = kt*16 + l15;
#pragma unroll
      for (int j = 0; j < 4; ++j) {
        if (colv >= NT) scr[kt][j] = -1e30f;
        mx[j] = fmaxf(mx[j], scr[kt][j]);
      }
    }
#pragma unroll
    for (int j = 0; j < 4; ++j) {
      mx[j] = fmaxf(mx[j], __shfl_xor(mx[j], 1));
      mx[j] = fmaxf(mx[j], __shfl_xor(mx[j], 2));
      mx[j] = fmaxf(mx[j], __shfl_xor(mx[j], 4));
      mx[j] = fmaxf(mx[j], __shfl_xor(mx[j], 8));
      sm[j] = 0.f;
    }
#pragma unroll
    for (int kt = 0; kt < 14; ++kt)
#pragma unroll
      for (int j = 0; j < 4; ++j) { float e = __expf(scr[kt][j] - mx[j]); scr[kt][j] = e; sm[j] += e; }
#pragma unroll
    for (int j = 0; j < 4; ++j) {
      sm[j] += __shfl_xor(sm[j], 1);
      sm[j] += __shfl_xor(sm[j], 2);
      sm[j] += __shfl_xor(sm[j], 4);
      sm[j] += __shfl_xor(sm[j], 8);
      sm[j] = 1.f / sm[j];
    }
    if (ti == 0 && l4 == 0) {   // query 0 lives in tile 0 (wave 0)
#pragma unroll
      for (int kt = 0; kt < 14; ++kt) {
        int colv = kt*16 + l15;
        if (colv >= 1 && colv < NT)
          atomicAdd(&cls[b*(NT-1) + colv - 1], scr[kt][0] * sm[0] * (1.f/NH));
      }
    }
#pragma unroll
    for (int kt = 0; kt < 14; ++kt) {
      int colv = kt*16 + l15;
#pragma unroll
      for (int j = 0; j < 4; ++j)
        p_lds[(l4*4 + j)*PSTR + colv] = f2bf(scr[kt][j] * sm[j]);
    }

    f32x4 ao[8] = {};
#pragma unroll
    for (int ks = 0; ks < 7; ++ks) {
      s16x8 ap = *(const s16x8*)&p_lds[l15*PSTR + ks*32 + l4*8];
#pragma unroll
      for (int dt = 0; dt < 8; ++dt) {
        const int vrow = (dt*16 + l15)*256;
        s16x8 bv = *(const s16x8*)&v_lds[vrow + (((ks*4 + l4) ^ kswz)*8)];
        ao[dt] = __builtin_amdgcn_mfma_f32_16x16x32_bf16(ap, bv, ao[dt], 0, 0, 0);
      }
    }
#pragma unroll
    for (int dt = 0; dt < 8; ++dt) {
      const int d = dt*16 + l15;
      const float av = sb[fv + d];
      const float bv = sb[HQKV + fv + d];
#pragma unroll
      for (int j = 0; j < 4; ++j) {
        int q = q0 + l4*4 + j;
        if (q < NT) {
          float v = ao[dt][j] * av + bv;
          float hs = v * fminf(fmaxf(v + 3.f, 0.f), 6.f) * (1.f/6.f);
          act[(rowBase + q)*DH + h*DV + d] = f2bf(hs);
        }
      }
    }
  }
}

// ---------------- final BN apply -> f32 out ----------------
__global__ void apply_bn(const bf16* __restrict__ y, const float* __restrict__ sb,
                         float* __restrict__ out)
{
  const int stride = gridDim.x * blockDim.x;
  for (int i = blockIdx.x * blockDim.x + threadIdx.x; i < MREAL*DIM/4; i += stride) {
    int c = (i*4) % DIM;
    u16x4 yv = *(const u16x4*)&y[(size_t)i*4];
    float4 o;
    o.x = u2f(yv.x) * sb[c]     + sb[DIM + c];
    o.y = u2f(yv.y) * sb[c + 1] + sb[DIM + c + 1];
    o.z = u2f(yv.z) * sb[c + 2] + sb[DIM + c + 2];
    o.w = u2f(yv.w) * sb[c + 3] + sb[DIM + c + 3];
    *(float4*)&out[(size_t)i*4] = o;
  }
}

extern "C" void kernel_launch(void* const* d_in, const int* in_sizes, int n_in,
                              void* d_out, int out_size, void* d_ws, size_t ws_size,
                              hipStream_t stream)
{
  const float* x      = (const float*)d_in[0];
  const float* qkv_w  = (const float*)d_in[1];
  const float* qkv_g  = (const float*)d_in[2];
  const float* qkv_b  = (const float*)d_in[3];
  const float* proj_w = (const float*)d_in[4];
  const float* proj_g = (const float*)d_in[5];
  const float* proj_b = (const float*)d_in[6];
  float* y_out   = (float*)d_out;
  float* cls_out = y_out + (size_t)MREAL * DIM;

  char* ws = (char*)d_ws;
  size_t off = 0;
  auto alloc = [&](size_t bytes) { void* p = ws + off; off += (bytes + 255) & ~(size_t)255; return p; };
  bf16* xb      = (bf16*)alloc((size_t)MPAD * DIM * 2);
  bf16* wqkvb   = (bf16*)alloc((size_t)HQKV * DIM * 2);
  bf16* wprojb  = (bf16*)alloc((size_t)DIM * DH * 2);
  bf16* qkv_raw = (bf16*)alloc((size_t)MPAD * HQKV * 2);
  bf16* act     = (bf16*)alloc((size_t)MPAD * DH * 2);
  bf16* y_raw   = (bf16*)alloc((size_t)MPAD * DIM * 2);
  bf16* vT      = (bf16*)alloc((size_t)NB * NH * DV * KPAD * 2);
  float* statq  = (float*)alloc((size_t)2 * HQKV * 4);
  float* sbq    = (float*)alloc((size_t)2 * HQKV * 4);
  float* statp  = (float*)alloc((size_t)2 * DIM * 4);
  float* sbp    = (float*)alloc((size_t)2 * DIM * 4);
  float* qcw    = (float*)alloc((size_t)NH * 128 * 4);

  prep_kernel<<<2048, 256, 0, stream>>>(x, qkv_w, proj_w, xb, wqkvb, wprojb, act, vT,
                                        statq, statp, cls_out);
  // qkv GEMM: 100 x 24 = 2400 blocks (2400 % 8 == 0 -> XCD swizzle on)
  gemm_m97<DIM, HQKV/128, true, true><<<(MPAD/128)*(HQKV/128), 256, 0, stream>>>(
      xb, wqkvb, qkv_raw, vT, statq, HQKV, (MPAD/128)*(HQKV/128));
  finalize_stats<<<HQKV/256, 256, 0, stream>>>(statq, qkv_g, qkv_b, sbq, HQKV, qcw);
  // attention: one block per (b,h) = 768 blocks, K/V staged in LDS once per block
  attn_kernel<<<NB*NH, 512, 0, stream>>>(qkv_raw, vT, sbq, qcw, act, cls_out);
  // proj GEMM: 100 x 6 = 600 blocks (swizzle on)
  gemm_m97<DH, DIM/128, false, true><<<(MPAD/128)*(DIM/128), 256, 0, stream>>>(
      act, wprojb, y_raw, nullptr, statp, DIM, (MPAD/128)*(DIM/128));
  finalize_stats<<<DIM/256, 256, 0, stream>>>(statp, proj_g, proj_b, sbp, DIM, nullptr);
  apply_bn<<<2048, 256, 0, stream>>>(y_raw, sbp, y_out);
}